// Round 7
// baseline (314.163 us; speedup 1.0000x reference)
//
#include <hip/hip_runtime.h>
#include <stdint.h>

// Problem constants
#define B_   8
#define S_   2047
#define L_   2048      // S+1 (CLS prepended)
#define H_   256       // HIDDEN
#define NH_  8
#define HD_  32
#define V_   32001     // VOCAB+1
#define NCH_ 256       // t-chunks per b
#define TCH_ 8         // t per chunk (NCH_*TCH_ == L_)
#define GRID_ 2048     // 8 blocks/CU x 256 CU -> co-resident
#define BAR_STRIDE_ 2048   // u32 per flag region (8 KB)

// ---------------------------------------------------------------------------
// LLC-direct (coherent) access via relaxed agent-scope atomics (sc0 sc1 on
// gfx950 -> bypass L1/XCD-L2). Proven correct rounds 4-6.
// ---------------------------------------------------------------------------
__device__ __forceinline__ void ast(float* p, float v) {
    __hip_atomic_store((unsigned int*)p, __float_as_uint(v),
                       __ATOMIC_RELAXED, __HIP_MEMORY_SCOPE_AGENT);
}
__device__ __forceinline__ float ald(const float* p) {
    return __uint_as_float(__hip_atomic_load((const unsigned int*)p,
                           __ATOMIC_RELAXED, __HIP_MEMORY_SCOPE_AGENT));
}
__device__ __forceinline__ unsigned aadd(unsigned* p) {
    return __hip_atomic_fetch_add(p, 1u, __ATOMIC_RELAXED, __HIP_MEMORY_SCOPE_AGENT);
}
__device__ __forceinline__ unsigned aldu(const unsigned* p) {
    return __hip_atomic_load(p, __ATOMIC_RELAXED, __HIP_MEMORY_SCOPE_AGENT);
}
__device__ __forceinline__ float foldx(float a, int off) {
    return a + __shfl_xor(a, off, 64);
}
__device__ __forceinline__ float sel8(const float a[8], int j) {
    float v = a[0];
    v = (j == 1) ? a[1] : v;
    v = (j == 2) ? a[2] : v;
    v = (j == 3) ? a[3] : v;
    v = (j == 4) ? a[4] : v;
    v = (j == 5) ? a[5] : v;
    v = (j == 6) ? a[6] : v;
    v = (j == 7) ? a[7] : v;
    return v;
}

// ---------------------------------------------------------------------------
// Mega kernel, point-to-point flags (no full-grid barriers):
//   P0 (blocks 0..7):        qk prep -> qk (LLC) -> qflag (32 release lines)
//   A  (all 2048, 8-t chunk): poll qflag; fused scores + ybar via LDS
//                             atomicAdd accum -> psum, esum (LLC) -> acnt++
//   B1 (last 64 blocks):     poll acnt==2048; chunk reduce -> ybar -> wv
//                             -> o_g -> b1cnt++
//   B2 (last 8 blocks):      poll b1cnt==64; z = wo·o + 2*y0 -> zflag (32 lines)
//   C  (all 2048, 16 rows):  issue wu loads FIRST (overlaps B1/B2), poll
//                             zflag, stage z in padded LDS, dot, write out.
// LDS 16.4 KB, VGPR<=64 (bounds 256,8) -> 8 blocks/CU -> 2048 co-resident.
// ---------------------------------------------------------------------------
__global__ __launch_bounds__(256, 8) void mega(const int* __restrict__ x,
                                               const float* __restrict__ emb,
                                               const float* __restrict__ wq,
                                               const float* __restrict__ wk,
                                               const float* __restrict__ wv,
                                               const float* __restrict__ wo,
                                               const float* __restrict__ wu,
                                               float* __restrict__ out,
                                               float* __restrict__ qk,
                                               float* __restrict__ z,
                                               float* __restrict__ o_g,
                                               float* __restrict__ esum_blk,
                                               float* __restrict__ psum,
                                               unsigned int* __restrict__ bars) {
    int bid = blockIdx.x, tid = threadIdx.x;

    __shared__ float smBig[4096];   // 16 KB, phase-aliased
    __shared__ float esA[NH_];

    unsigned* qbar  = bars;                    // [0]=cnt, [528+i*16]=rel_i
    unsigned* acnt  = bars + BAR_STRIDE_;      // [0]
    unsigned* b1cnt = bars + 2 * BAR_STRIDE_;  // [0]
    unsigned* zbar  = bars + 3 * BAR_STRIDE_;  // [0]=cnt, [528+i*16]=rel_i

    // ---- P0: qk prep (blocks 0..7) ----
    if (bid < NH_) {
        int n = bid;
        float* y0l = smBig;          // [256]
        float* q0p = smBig + 256;    // [256] = [k*8+p]
        float* q0l = smBig + 512;    // [32]
        float v = emb[2 * H_ + tid] + ((tid & 1) ? 1.0f : 0.0f);  // pe[0]
        y0l[tid] = v;
        __syncthreads();
        {
            int k = tid >> 3, part = tid & 7;
            const float* w = wq + (n * HD_ + k) * H_ + part * 32;
            const float* yy = y0l + part * 32;
            float acc = 0.f;
#pragma unroll
            for (int j = 0; j < 32; ++j) acc += w[j] * yy[j];
            q0p[k * 8 + part] = acc;
        }
        __syncthreads();
        if (tid < HD_) {
            float s = 0.f;
#pragma unroll
            for (int j = 0; j < 8; ++j) s += q0p[tid * 8 + j];
            q0l[tid] = s;
        }
        __syncthreads();
        float acc = 0.f;
        for (int k = 0; k < HD_; ++k)
            acc += q0l[k] * wk[(n * HD_ + k) * H_ + tid];
        ast(qk + n * H_ + tid, acc * 0.17677669529663687f);  // 1/sqrt(32)
        __syncthreads();   // drain qk stores (vmcnt 0 before barrier)
        if (tid == 0) {
            if (aadd(qbar) == NH_ - 1) {
                for (int i = 0; i < 32; ++i)
                    __hip_atomic_store(qbar + 528 + i * 16, 1u,
                                       __ATOMIC_RELAXED, __HIP_MEMORY_SCOPE_AGENT);
            }
        }
    }

    // ---- A: fused scores + ybar (all blocks, 8-t chunk, 2 t/wave) ----
    {
        int b = bid >> 8, c = bid & 255;
        int lane = tid & 63, w = tid >> 6;
        int h0 = lane * 4;
        int t0 = c * TCH_ + w * 2;

        // issue gathers + trig BEFORE qk poll (overlaps P0)
        int tok0 = (t0 == 0) ? 2 : x[b * S_ + t0 - 1];
        int tok1 = x[b * S_ + t0];   // t = t0+1 >= 1 always
        float4 ev0 = *(const float4*)(emb + (size_t)tok0 * H_ + h0);
        float4 ev1 = *(const float4*)(emb + (size_t)tok1 * H_ + h0);
        const float cdiv = 0.07195578414202881f;  // ln(10000)/128
        float div0 = __expf(-(float)(lane * 2) * cdiv);
        float div1 = __expf(-(float)(lane * 2 + 1) * cdiv);

        for (int i = tid; i < NH_ * H_; i += 256) smBig[i] = 0.f;  // accumA
        if (tid < NH_) esA[tid] = 0.f;
        __builtin_amdgcn_sched_barrier(0);

        if (tid == 0) {
            while (aldu(qbar + 528 + (bid & 31) * 16) == 0u)
                __builtin_amdgcn_s_sleep(2);
        }
        __syncthreads();

        float* qk_l = smBig + 2048;
        for (int i = tid; i < NH_ * H_; i += 256) qk_l[i] = ald(qk + i);
        __syncthreads();

#pragma unroll
        for (int it = 0; it < 2; ++it) {
            int t = t0 + it;
            float4 ev = it ? ev1 : ev0;
            float a0 = (float)t * div0, a1 = (float)t * div1;
            float4 y4;
            y4.x = ev.x + __sinf(a0); y4.y = ev.y + __cosf(a0);
            y4.z = ev.z + __sinf(a1); y4.w = ev.w + __cosf(a1);

            float a[NH_];
#pragma unroll
            for (int n = 0; n < NH_; ++n) {
                float4 q4 = *(const float4*)&qk_l[n * H_ + h0];
                a[n] = q4.x * y4.x + q4.y * y4.y + q4.z * y4.z + q4.w * y4.w;
            }
            float m4[4];
#pragma unroll
            for (int k = 0; k < 4; ++k) {
                float lo = foldx(a[k], 32), hi = foldx(a[k + 4], 32);
                m4[k] = (lane & 32) ? hi : lo;
            }
            float m2[2];
#pragma unroll
            for (int k = 0; k < 2; ++k) {
                float lo = foldx(m4[k], 16), hi = foldx(m4[k + 2], 16);
                m2[k] = (lane & 16) ? hi : lo;
            }
            float lo = foldx(m2[0], 8), hi = foldx(m2[1], 8);
            float m1 = (lane & 8) ? hi : lo;
            m1 = foldx(m1, 4); m1 = foldx(m1, 2); m1 = foldx(m1, 1);
            float e = __expf(m1);  // lane n*8 holds head n's score

#pragma unroll
            for (int n = 0; n < NH_; ++n) {
                float en = __shfl(e, n * 8, 64);
                atomicAdd(&smBig[n * H_ + h0 + 0], en * y4.x);
                atomicAdd(&smBig[n * H_ + h0 + 1], en * y4.y);
                atomicAdd(&smBig[n * H_ + h0 + 2], en * y4.z);
                atomicAdd(&smBig[n * H_ + h0 + 3], en * y4.w);
            }
            if ((lane & 7) == 0) atomicAdd(&esA[lane >> 3], e);
        }
        __syncthreads();

#pragma unroll
        for (int jj = 0; jj < (NH_ * H_) / 256; ++jj) {
            int j = jj * 256 + tid;
            ast(psum + (size_t)bid * (NH_ * H_) + j, smBig[j]);
        }
        if (tid < NH_) ast(esum_blk + bid * NH_ + tid, esA[tid]);
        __syncthreads();   // drain psum/esum stores
        if (tid == 0) aadd(acnt);
    }

    // ---- B1: per-(b,n) chunk reduce -> ybar -> wv -> o_g (last 64) ----
    if (bid >= GRID_ - 64) {
        int id = bid - (GRID_ - 64);
        int b = id >> 3, n = id & 7;
        if (tid == 0) {
            while (aldu(acnt) < (unsigned)GRID_) __builtin_amdgcn_s_sleep(2);
        }
        __syncthreads();
        float* es_l = smBig;           // [256]
        float* ybar = smBig + 256;     // [256]
        float* opb  = smBig + 512;     // [256]; sinv at smBig[768]
        es_l[tid] = ald(esum_blk + (size_t)(b * NCH_ + tid) * NH_ + n);
        __syncthreads();
        if (tid < 64) {
            float v = es_l[tid] + es_l[tid + 64] + es_l[tid + 128] + es_l[tid + 192];
#pragma unroll
            for (int off = 32; off > 0; off >>= 1) v += __shfl_xor(v, off, 64);
            if (tid == 0) smBig[768] = 1.0f / v;
        }
        __syncthreads();
        {
            const float* pp = psum + (size_t)(b * NCH_) * (NH_ * H_) + n * H_ + tid;
            float s = 0.f;
#pragma unroll 16
            for (int cc = 0; cc < NCH_; ++cc) s += ald(pp + (size_t)cc * (NH_ * H_));
            ybar[tid] = s * smBig[768];
        }
        __syncthreads();
        {
            int k = tid >> 3, p = tid & 7;
            const float* wrow = wv + (size_t)(n * HD_ + k) * H_ + p * 32;
            const float* yy = ybar + p * 32;
            float s = 0.f;
#pragma unroll
            for (int j = 0; j < 32; ++j) s += wrow[j] * yy[j];
            opb[k * 8 + p] = s;
        }
        __syncthreads();
        if (tid < HD_) {
            float s = 0.f;
#pragma unroll
            for (int p = 0; p < 8; ++p) s += opb[tid * 8 + p];
            ast(o_g + b * (NH_ * HD_) + n * HD_ + tid, s);
        }
        __syncthreads();   // drain o_g stores
        if (tid == 0) aadd(b1cnt);
    }

    // ---- B2: z = wo·o + 2*y0 (last 8) ----
    if (bid >= GRID_ - 8) {
        int b = bid - (GRID_ - 8);
        if (tid == 0) {
            while (aldu(b1cnt) < 64u) __builtin_amdgcn_s_sleep(2);
        }
        __syncthreads();
        float* o_l = smBig;
        o_l[tid] = ald(o_g + b * (NH_ * HD_) + tid);
        float y0v = emb[2 * H_ + tid] + ((tid & 1) ? 1.0f : 0.0f);
        __syncthreads();
        const float* wrow = wo + (size_t)tid * (NH_ * HD_);
        float s = 0.f;
#pragma unroll 16
        for (int j4 = 0; j4 < (NH_ * HD_) / 4; ++j4) {
            float4 w4 = *(const float4*)(wrow + j4 * 4);
            s += w4.x * o_l[j4 * 4] + w4.y * o_l[j4 * 4 + 1]
               + w4.z * o_l[j4 * 4 + 2] + w4.w * o_l[j4 * 4 + 3];
        }
        ast(z + b * H_ + tid, s + 2.0f * y0v);
        __syncthreads();   // drain z stores
        if (tid == 0) {
            if (aadd(zbar) == 7u) {
                for (int i = 0; i < 32; ++i)
                    __hip_atomic_store(zbar + 528 + i * 16, 1u,
                                       __ATOMIC_RELAXED, __HIP_MEMORY_SCOPE_AGENT);
            }
        }
    }

    // ---- C: out = z · wu^T (all blocks, 16 vocab rows each) ----
    {
        int lane = tid & 63, w = tid >> 6;
        int m = lane & 15, g = lane >> 4;
        int base = bid * 16;
        int rl = w * 4 + g;
        int v = base + rl;
        int vc = (v < V_) ? v : (V_ - 1);
        const float* wr = wu + (size_t)vc * H_ + m * 16;
        // issue wu loads BEFORE the z poll (overlaps B1+B2)
        float4 w0 = *(const float4*)(wr);
        float4 w1 = *(const float4*)(wr + 4);
        float4 w2 = *(const float4*)(wr + 8);
        float4 w3 = *(const float4*)(wr + 12);
        __builtin_amdgcn_sched_barrier(0);

        if (tid == 0) {
            while (aldu(zbar + 528 + (bid & 31) * 16) == 0u)
                __builtin_amdgcn_s_sleep(4);
        }
        __syncthreads();

        // stage z: padded [b*320 + (h>>4)*20 + (h&15)] -> broadcast-friendly
        float* zs = smBig;              // [2560]
        float* sm_out = smBig + 2560;   // [8*17]
        for (int i = tid; i < B_ * H_; i += 256) {
            int bb = i >> 8, h = i & 255;
            zs[bb * 320 + (h >> 4) * 20 + (h & 15)] = ald(z + i);
        }
        __syncthreads();

        float acc[B_];
#pragma unroll
        for (int bb = 0; bb < B_; ++bb) {
            const float* zb = zs + bb * 320 + m * 20;
            float4 z0 = *(const float4*)(zb);
            float4 z1 = *(const float4*)(zb + 4);
            float4 z2 = *(const float4*)(zb + 8);
            float4 z3 = *(const float4*)(zb + 12);
            acc[bb] = z0.x * w0.x + z0.y * w0.y + z0.z * w0.z + z0.w * w0.w
                    + z1.x * w1.x + z1.y * w1.y + z1.z * w1.z + z1.w * w1.w
                    + z2.x * w2.x + z2.y * w2.y + z2.z * w2.z + z2.w * w2.w
                    + z3.x * w3.x + z3.y * w3.y + z3.z * w3.z + z3.w * w3.w;
        }
#pragma unroll
        for (int off = 1; off <= 8; off <<= 1) {
#pragma unroll
            for (int bb = 0; bb < B_; ++bb) acc[bb] += __shfl_xor(acc[bb], off, 64);
        }
        if (m < B_) sm_out[m * 17 + rl] = sel8(acc, m);
        __syncthreads();
        if (tid < B_ * 16) {
            int bb = tid >> 4, vl = tid & 15, vv = base + vl;
            if (vv < V_) out[bb * V_ + vv] = sm_out[bb * 17 + vl];
        }
    }
}

// ---------------------------------------------------------------------------
extern "C" void kernel_launch(void* const* d_in, const int* in_sizes, int n_in,
                              void* d_out, int out_size, void* d_ws, size_t ws_size,
                              hipStream_t stream) {
    const int*   x   = (const int*)d_in[0];
    const float* emb = (const float*)d_in[1];
    const float* wq  = (const float*)d_in[2];
    const float* wk  = (const float*)d_in[3];
    const float* wv  = (const float*)d_in[4];
    const float* wo  = (const float*)d_in[5];
    const float* wu  = (const float*)d_in[6];
    float*       out = (float*)d_out;

    // ws layout (floats unless noted), ~17 MiB:
    // qk[2048] | z[2048] | o_g[2048] | esum_blk[2048*8] | psum[2048*2048]
    // | bars[4*2048 u32]
    float* qk       = (float*)d_ws;
    float* z        = qk + NH_ * H_;
    float* o_g      = z + B_ * H_;
    float* esum_blk = o_g + B_ * NH_ * HD_;
    float* psum     = esum_blk + (size_t)GRID_ * NH_;
    unsigned int* bars = (unsigned int*)(psum + (size_t)GRID_ * NH_ * H_);

    // Zero the flag counters (workspace is poisoned each iteration).
    hipMemsetAsync(bars, 0, 4 * BAR_STRIDE_ * sizeof(unsigned int), stream);

    mega<<<GRID_, 256, 0, stream>>>(x, emb, wq, wk, wv, wo, wu, out,
                                    qk, z, o_g, esum_blk, psum, bars);
}

// Round 8
// 160.702 us; speedup vs baseline: 1.9549x; 1.9549x over previous
//
#include <hip/hip_runtime.h>
#include <stdint.h>

// Problem constants
#define B_   8
#define S_   2047
#define L_   2048      // S+1 (CLS prepended)
#define H_   256       // HIDDEN
#define NH_  8
#define HD_  32
#define V_   32001     // VOCAB+1
#define NCH_ 128       // t-chunks per b
#define TCH_ 16        // t per chunk (NCH_*TCH_ == L_)
#define GRID_ 1024     // 4 blocks/CU x 256 CU -> co-resident (proven r6)
#define BAR_STRIDE_ 2048   // u32 per flag region (8 KB)

// ---------------------------------------------------------------------------
// LLC-direct (coherent) access via relaxed agent-scope atomics (sc0 sc1 on
// gfx950 -> bypass L1/XCD-L2). Proven correct rounds 4-7.
// ---------------------------------------------------------------------------
__device__ __forceinline__ void ast(float* p, float v) {
    __hip_atomic_store((unsigned int*)p, __float_as_uint(v),
                       __ATOMIC_RELAXED, __HIP_MEMORY_SCOPE_AGENT);
}
__device__ __forceinline__ float ald(const float* p) {
    return __uint_as_float(__hip_atomic_load((const unsigned int*)p,
                           __ATOMIC_RELAXED, __HIP_MEMORY_SCOPE_AGENT));
}
__device__ __forceinline__ unsigned aadd(unsigned* p) {
    return __hip_atomic_fetch_add(p, 1u, __ATOMIC_RELAXED, __HIP_MEMORY_SCOPE_AGENT);
}
__device__ __forceinline__ unsigned aldu(const unsigned* p) {
    return __hip_atomic_load(p, __ATOMIC_RELAXED, __HIP_MEMORY_SCOPE_AGENT);
}
__device__ __forceinline__ void vdrain() {     // belt+braces store/atomic drain
    asm volatile("s_waitcnt vmcnt(0)" ::: "memory");
}
__device__ __forceinline__ float foldx(float a, int off) {
    return a + __shfl_xor(a, off, 64);
}
__device__ __forceinline__ float sel8(const float a[8], int j) {
    float v = a[0];
    v = (j == 1) ? a[1] : v;
    v = (j == 2) ? a[2] : v;
    v = (j == 3) ? a[3] : v;
    v = (j == 4) ? a[4] : v;
    v = (j == 5) ? a[5] : v;
    v = (j == 6) ? a[6] : v;
    v = (j == 7) ? a[7] : v;
    return v;
}

// ---------------------------------------------------------------------------
// Mega kernel, point-to-point flags, NO full-grid barriers:
//   P0 (blocks 0..7):  qk prep -> qk (LLC) -> qflag (32 release lines)
//   A  (all 1024):     prefetch toks/emb/trig; poll qflag; round-6 A body
//                      (reg acc + cross-wave LDS reduce); then global
//                      atomicAdd into obar[b][n][h], ebar[b][n] -> acnt++
//   B  (blocks 8..15): poll acnt==1024; ybar=obar/ebar -> wv -> wo
//                      -> z = . + 2*y0 -> zflag (32 release lines)
//   C  (all, 32 rows): prefetch pass-0 wu rows (overlaps B); poll zflag;
//                      stage z padded in LDS; 2 passes; write out.
// LDS 32.9 KB, launch_bounds(256,4) (proven: VGPR<=128, no spills)
// -> 4 blocks/CU -> 1024 co-resident -> flag protocol deadlock-free.
// ---------------------------------------------------------------------------
__global__ __launch_bounds__(256, 4) void mega(const int* __restrict__ x,
                                               const float* __restrict__ emb,
                                               const float* __restrict__ wq,
                                               const float* __restrict__ wk,
                                               const float* __restrict__ wv,
                                               const float* __restrict__ wo,
                                               const float* __restrict__ wu,
                                               float* __restrict__ out,
                                               float* __restrict__ qk,
                                               float* __restrict__ z,
                                               float* __restrict__ obar,
                                               float* __restrict__ ebar,
                                               unsigned int* __restrict__ bars) {
    int bid = blockIdx.x, tid = threadIdx.x;

    __shared__ float smem[4][2056];          // 32.9 KB, phase-aliased
    float* smf = &smem[0][0];

    unsigned* qbar = bars;                    // [0]=cnt, [528+i*16]=rel_i
    unsigned* acnt = bars + BAR_STRIDE_;      // [0]
    unsigned* zbar = bars + 2 * BAR_STRIDE_;  // [0]=cnt, [528+i*16]=rel_i

    // ---- P0: qk prep (blocks 0..7) ----
    if (bid < NH_) {
        int n = bid;
        float* y0l = smem[0];
        float* q0p = smem[1];   // [k*8+p]
        float* q0l = smem[2];
        float v = emb[2 * H_ + tid] + ((tid & 1) ? 1.0f : 0.0f);  // pe[0]
        y0l[tid] = v;
        __syncthreads();
        {
            int k = tid >> 3, part = tid & 7;
            const float* w = wq + (n * HD_ + k) * H_ + part * 32;
            const float* yy = y0l + part * 32;
            float acc = 0.f;
#pragma unroll
            for (int j = 0; j < 32; ++j) acc += w[j] * yy[j];
            q0p[k * 8 + part] = acc;
        }
        __syncthreads();
        if (tid < HD_) {
            float s = 0.f;
#pragma unroll
            for (int j = 0; j < 8; ++j) s += q0p[tid * 8 + j];
            q0l[tid] = s;
        }
        __syncthreads();
        float acc = 0.f;
        for (int k = 0; k < HD_; ++k)
            acc += q0l[k] * wk[(n * HD_ + k) * H_ + tid];
        ast(qk + n * H_ + tid, acc * 0.17677669529663687f);  // 1/sqrt(32)
        vdrain();
        __syncthreads();
        if (tid == 0) {
            if (aadd(qbar) == NH_ - 1) {
                for (int i = 0; i < 32; ++i)
                    __hip_atomic_store(qbar + 528 + i * 16, 1u,
                                       __ATOMIC_RELAXED, __HIP_MEMORY_SCOPE_AGENT);
            }
        }
        __syncthreads();
    }

    // ---- A: fused scores + ybar chunk contribution (all 1024 blocks) ----
    {
        int b = bid >> 7, c = bid & 127;
        int lane = tid & 63, w = tid >> 6;
        int h0 = lane * 4;
        int t0 = c * TCH_ + w * 4;

        // prefetch: tokens, emb rows, trig divisors (independent of qk)
        int toks[4];
#pragma unroll
        for (int i = 0; i < 4; ++i) {
            int t = t0 + i;
            toks[i] = (t == 0) ? 2 : x[b * S_ + t - 1];
        }
        float4 evr[4];
#pragma unroll
        for (int i = 0; i < 4; ++i)
            evr[i] = *(const float4*)(emb + (size_t)toks[i] * H_ + h0);
        const float cdiv = 0.07195578414202881f;  // ln(10000)/128
        float div0 = __expf(-(float)(lane * 2) * cdiv);
        float div1 = __expf(-(float)(lane * 2 + 1) * cdiv);
        __builtin_amdgcn_sched_barrier(0);

        if (tid == 0) {
            while (aldu(qbar + 528 + (bid & 31) * 16) == 0u)
                __builtin_amdgcn_s_sleep(2);
        }
        __syncthreads();

        // stage qk into smem[3]; freed after qr load
        for (int i = tid; i < NH_ * H_; i += 256)
            smem[3][i] = ald(qk + i);
        __syncthreads();
        float4 qr[NH_];
#pragma unroll
        for (int n = 0; n < NH_; ++n)
            qr[n] = *(const float4*)&smem[3][n * H_ + h0];
        __syncthreads();   // smem[3] now dead -> red[3]

        float4 acc[NH_];
        float es[NH_];
#pragma unroll
        for (int n = 0; n < NH_; ++n) {
            acc[n] = make_float4(0.f, 0.f, 0.f, 0.f);
            es[n] = 0.f;
        }

#pragma unroll
        for (int i = 0; i < 4; ++i) {
            int t = t0 + i;
            float4 ev = evr[i];
            float a0 = (float)t * div0, a1 = (float)t * div1;
            float4 y4;
            y4.x = ev.x + __sinf(a0); y4.y = ev.y + __cosf(a0);
            y4.z = ev.z + __sinf(a1); y4.w = ev.w + __cosf(a1);

            float a[NH_];
#pragma unroll
            for (int n = 0; n < NH_; ++n)
                a[n] = qr[n].x * y4.x + qr[n].y * y4.y + qr[n].z * y4.z + qr[n].w * y4.w;

            float m4[4];
#pragma unroll
            for (int k = 0; k < 4; ++k) {
                float lo = foldx(a[k], 32), hi = foldx(a[k + 4], 32);
                m4[k] = (lane & 32) ? hi : lo;
            }
            float m2[2];
#pragma unroll
            for (int k = 0; k < 2; ++k) {
                float lo = foldx(m4[k], 16), hi = foldx(m4[k + 2], 16);
                m2[k] = (lane & 16) ? hi : lo;
            }
            float lo = foldx(m2[0], 8), hi = foldx(m2[1], 8);
            float m1 = (lane & 8) ? hi : lo;
            m1 = foldx(m1, 4); m1 = foldx(m1, 2); m1 = foldx(m1, 1);
            float e = __expf(m1);  // lane n*8 holds head n's score

#pragma unroll
            for (int n = 0; n < NH_; ++n) {
                float en = __shfl(e, n * 8, 64);
                acc[n].x += en * y4.x; acc[n].y += en * y4.y;
                acc[n].z += en * y4.z; acc[n].w += en * y4.w;
                es[n] += en;
            }
        }

#pragma unroll
        for (int n = 0; n < NH_; ++n)
            *(float4*)&smem[w][n * H_ + h0] = acc[n];
        if (lane < NH_) smem[w][2048 + lane] = sel8(es, lane);
        __syncthreads();

        // global f32 atomics into obar/ebar (device scope, LLC-coherent)
#pragma unroll
        for (int jj = 0; jj < (NH_ * H_) / 256; ++jj) {
            int j = jj * 256 + tid;
            atomicAdd(obar + b * (NH_ * H_) + j,
                      smem[0][j] + smem[1][j] + smem[2][j] + smem[3][j]);
        }
        if (tid < NH_)
            atomicAdd(ebar + b * NH_ + tid,
                      smem[0][2048 + tid] + smem[1][2048 + tid]
                    + smem[2][2048 + tid] + smem[3][2048 + tid]);
        vdrain();
        __syncthreads();
        if (tid == 0) aadd(acnt);
    }

    // ---- B: per-b normalize -> wv -> wo -> z (blocks 8..15) ----
    if (bid >= 8 && bid < 16) {
        int b = bid - 8;
        if (tid == 0) {
            while (aldu(acnt) < (unsigned)GRID_) __builtin_amdgcn_s_sleep(2);
        }
        __syncthreads();
        float* ybar_l = smf;            // [2048]
        float* o_l    = smf + 2048;     // [256]
        float* sB     = smf + 2304;     // [8]
        if (tid < NH_) sB[tid] = 1.0f / ald(ebar + b * NH_ + tid);
        __syncthreads();
        for (int i = tid; i < NH_ * H_; i += 256)
            ybar_l[i] = ald(obar + b * (NH_ * H_) + i) * sB[i >> 8];
        __syncthreads();
        {   // wv: thread tid = n*32+k computes o[tid]
            int n = tid >> 5;
            const float* wrow = wv + (size_t)tid * H_;
            const float* yy = ybar_l + n * H_;
            float s = 0.f;
#pragma unroll 16
            for (int j4 = 0; j4 < H_ / 4; ++j4) {
                float4 w4 = *(const float4*)(wrow + j4 * 4);
                s += w4.x * yy[j4 * 4] + w4.y * yy[j4 * 4 + 1]
                   + w4.z * yy[j4 * 4 + 2] + w4.w * yy[j4 * 4 + 3];
            }
            o_l[tid] = s;
        }
        __syncthreads();
        {   // wo + double residual
            float y0v = emb[2 * H_ + tid] + ((tid & 1) ? 1.0f : 0.0f);
            const float* wrow = wo + (size_t)tid * (NH_ * HD_);
            float s = 0.f;
#pragma unroll 16
            for (int j4 = 0; j4 < (NH_ * HD_) / 4; ++j4) {
                float4 w4 = *(const float4*)(wrow + j4 * 4);
                s += w4.x * o_l[j4 * 4] + w4.y * o_l[j4 * 4 + 1]
                   + w4.z * o_l[j4 * 4 + 2] + w4.w * o_l[j4 * 4 + 3];
            }
            ast(z + b * H_ + tid, s + 2.0f * y0v);
        }
        vdrain();
        __syncthreads();
        if (tid == 0) {
            if (aadd(zbar) == B_ - 1) {
                for (int i = 0; i < 32; ++i)
                    __hip_atomic_store(zbar + 528 + i * 16, 1u,
                                       __ATOMIC_RELAXED, __HIP_MEMORY_SCOPE_AGENT);
            }
        }
        __syncthreads();
    }

    // ---- C: out = z · wu^T (all blocks, 32 vocab rows each) ----
    {
        int lane = tid & 63, w = tid >> 6;
        int m = lane & 15, g = lane >> 4;
        int base = bid * 32;

        // pass-0 wu prefetch BEFORE the z poll (overlaps B)
        int rl0 = w * 4 + g;
        int v0 = base + rl0;
        int vc0 = (v0 < V_) ? v0 : (V_ - 1);
        const float* wr0 = wu + (size_t)vc0 * H_ + m * 16;
        float4 p00 = *(const float4*)(wr0);
        float4 p01 = *(const float4*)(wr0 + 4);
        float4 p02 = *(const float4*)(wr0 + 8);
        float4 p03 = *(const float4*)(wr0 + 12);
        __builtin_amdgcn_sched_barrier(0);

        if (tid == 0) {
            while (aldu(zbar + 528 + (bid & 31) * 16) == 0u)
                __builtin_amdgcn_s_sleep(2);
        }
        __syncthreads();

        // stage z padded: zs[b*320 + (h>>4)*20 + (h&15)]
        float* zs = smf;                // [2560]
        float* sm_out = smf + 2560;     // [8*33]
        for (int i = tid; i < B_ * H_; i += 256) {
            int bb = i >> 8, h = i & 255;
            zs[bb * 320 + (h >> 4) * 20 + (h & 15)] = ald(z + i);
        }
        __syncthreads();

#pragma unroll
        for (int pass = 0; pass < 2; ++pass) {
            int rl = pass * 16 + w * 4 + g;
            float4 w0, w1, w2, w3;
            if (pass == 0) { w0 = p00; w1 = p01; w2 = p02; w3 = p03; }
            else {
                int v = base + rl;
                int vc = (v < V_) ? v : (V_ - 1);
                const float* wr = wu + (size_t)vc * H_ + m * 16;
                w0 = *(const float4*)(wr);
                w1 = *(const float4*)(wr + 4);
                w2 = *(const float4*)(wr + 8);
                w3 = *(const float4*)(wr + 12);
            }
            float acc[B_];
#pragma unroll
            for (int bb = 0; bb < B_; ++bb) {
                const float* zb = zs + bb * 320 + m * 20;
                float4 z0 = *(const float4*)(zb);
                float4 z1 = *(const float4*)(zb + 4);
                float4 z2 = *(const float4*)(zb + 8);
                float4 z3 = *(const float4*)(zb + 12);
                acc[bb] = z0.x * w0.x + z0.y * w0.y + z0.z * w0.z + z0.w * w0.w
                        + z1.x * w1.x + z1.y * w1.y + z1.z * w1.z + z1.w * w1.w
                        + z2.x * w2.x + z2.y * w2.y + z2.z * w2.z + z2.w * w2.w
                        + z3.x * w3.x + z3.y * w3.y + z3.z * w3.z + z3.w * w3.w;
            }
#pragma unroll
            for (int off = 1; off <= 8; off <<= 1) {
#pragma unroll
                for (int bb = 0; bb < B_; ++bb) acc[bb] += __shfl_xor(acc[bb], off, 64);
            }
            if (m < B_) sm_out[m * 33 + rl] = sel8(acc, m);
        }
        __syncthreads();
        {
            int bb = tid >> 5, vl = tid & 31, vv = base + vl;
            if (vv < V_) out[bb * V_ + vv] = sm_out[bb * 33 + vl];
        }
    }
}

// ---------------------------------------------------------------------------
extern "C" void kernel_launch(void* const* d_in, const int* in_sizes, int n_in,
                              void* d_out, int out_size, void* d_ws, size_t ws_size,
                              hipStream_t stream) {
    const int*   x   = (const int*)d_in[0];
    const float* emb = (const float*)d_in[1];
    const float* wq  = (const float*)d_in[2];
    const float* wk  = (const float*)d_in[3];
    const float* wv  = (const float*)d_in[4];
    const float* wo  = (const float*)d_in[5];
    const float* wu  = (const float*)d_in[6];
    float*       out = (float*)d_out;

    // ws layout (floats unless noted), ~100 KB:
    // qk[2048] | z[2048] | obar[8*2048] | ebar[64] | bars[3*2048 u32]
    float* qk   = (float*)d_ws;
    float* z    = qk + NH_ * H_;
    float* obar = z + B_ * H_;
    float* ebar = obar + B_ * NH_ * H_;
    unsigned int* bars = (unsigned int*)(ebar + B_ * NH_);

    // Zero accumulators + flags (workspace is poisoned each iteration).
    hipMemsetAsync(obar, 0,
                   (B_ * NH_ * H_ + B_ * NH_) * sizeof(float)
                 + 3 * BAR_STRIDE_ * sizeof(unsigned int), stream);

    mega<<<GRID_, 256, 0, stream>>>(x, emb, wq, wk, wv, wo, wu, out,
                                    qk, z, obar, ebar, bars);
}